// Round 1
// baseline (604.311 us; speedup 1.0000x reference)
//
#include <hip/hip_runtime.h>
#include <math.h>

#define ALPHA 0.2f

// ---------------- Kernel 1: h = X @ W, node scores s_src/s_tgt --------------
__global__ __launch_bounds__(256) void k_h_scores(
    const float* __restrict__ X, const float* __restrict__ W,
    const float* __restrict__ a, float* __restrict__ h,
    float* __restrict__ s_src, float* __restrict__ s_tgt, int N)
{
    __shared__ float Ws[64 * 64];
    __shared__ float xs[4][64];
    const int tid  = threadIdx.x;
    const int lane = tid & 63;
    const int wave = tid >> 6;
    const int row  = blockIdx.x * 4 + wave;

    for (int i = tid; i < 64 * 64; i += 256) Ws[i] = W[i];
    if (row < N) xs[wave][lane] = X[(size_t)row * 64 + lane];
    __syncthreads();

    if (row >= N) return;

    float acc = 0.f;
#pragma unroll
    for (int k = 0; k < 64; ++k) acc += xs[wave][k] * Ws[k * 64 + lane];

    h[(size_t)row * 64 + lane] = acc;

    float v1 = acc * a[lane];
    float v2 = acc * a[64 + lane];
#pragma unroll
    for (int off = 32; off > 0; off >>= 1) {
        v1 += __shfl_xor(v1, off);
        v2 += __shfl_xor(v2, off);
    }
    if (lane == 0) { s_src[row] = v1; s_tgt[row] = v2; }
}

// ---------------- ordered-uint float encoding for atomic max ----------------
__device__ __forceinline__ unsigned f32_ord(float f) {
    unsigned u = __float_as_uint(f);
    return (u & 0x80000000u) ? ~u : (u | 0x80000000u);
}
__device__ __forceinline__ float ord_f32(unsigned u) {
    u = (u & 0x80000000u) ? (u & 0x7FFFFFFFu) : ~u;
    return __uint_as_float(u);
}

// ---------------- Kernel 2: edge score + segment max ------------------------
__global__ __launch_bounds__(256) void k_edge_max(
    const int* __restrict__ src, const int* __restrict__ tgt,
    const float* __restrict__ s_src, const float* __restrict__ s_tgt,
    float* __restrict__ e_buf, unsigned* __restrict__ m_ord, int E)
{
    int i = blockIdx.x * 256 + threadIdx.x;
    if (i >= E) return;
    int s = src[i], t = tgt[i];
    float e = s_src[s] + s_tgt[t];
    e = (e >= 0.f) ? e : ALPHA * e;
    e_buf[i] = e;
    atomicMax(&m_ord[t], f32_ord(e));
}

// ---------------- Kernel 3: exp(e - m[tgt]) + segment sum -------------------
__global__ __launch_bounds__(256) void k_edge_exp(
    const int* __restrict__ tgt, const unsigned* __restrict__ m_ord,
    float* __restrict__ e_buf, float* __restrict__ denom, int E)
{
    int i = blockIdx.x * 256 + threadIdx.x;
    if (i >= E) return;
    int t = tgt[i];
    float ex = expf(e_buf[i] - ord_f32(m_ord[t]));
    e_buf[i] = ex;
    atomicAdd(&denom[t], ex);
}

// ---------------- Kernel 4: attention = e_exp / denom[tgt] ------------------
__global__ __launch_bounds__(256) void k_att(
    const int* __restrict__ tgt, const float* __restrict__ denom,
    float* __restrict__ e_buf, int E)
{
    int i = blockIdx.x * 256 + threadIdx.x;
    if (i >= E) return;
    e_buf[i] = e_buf[i] / denom[tgt[i]];
}

// ---------------- Kernel 5: weighted scatter-add ----------------------------
__global__ __launch_bounds__(256) void k_scatter(
    const int* __restrict__ src, const int* __restrict__ tgt,
    const float* __restrict__ h, const float* __restrict__ att,
    float* __restrict__ out, int E)
{
    int g = blockIdx.x * 256 + threadIdx.x;
    int i = g >> 6;
    int j = g & 63;
    if (i >= E) return;
    float v = h[(size_t)src[i] * 64 + j] * att[i];
    atomicAdd(&out[(size_t)tgt[i] * 64 + j], v);
}

// ---------------- Kernel 6: ELU in place ------------------------------------
__global__ __launch_bounds__(256) void k_elu(float* __restrict__ out, int n) {
    int i = blockIdx.x * 256 + threadIdx.x;
    if (i >= n) return;
    float x = out[i];
    out[i] = (x > 0.f) ? x : expm1f(x);
}

extern "C" void kernel_launch(void* const* d_in, const int* in_sizes, int n_in,
                              void* d_out, int out_size, void* d_ws, size_t ws_size,
                              hipStream_t stream)
{
    const float* X  = (const float*)d_in[0];
    const int*   ei = (const int*)d_in[1];
    const float* W  = (const float*)d_in[2];
    const float* a  = (const float*)d_in[3];

    const int N = in_sizes[0] / 64;
    const int E = in_sizes[1] / 2;
    const int* src = ei;
    const int* tgt = ei + E;

    float* out = (float*)d_out;

    char* ws = (char*)d_ws;
    float*    h     = (float*)ws;    ws += (size_t)N * 64 * sizeof(float);
    float*    e_buf = (float*)ws;    ws += (size_t)E * sizeof(float);
    unsigned* m_ord = (unsigned*)ws; ws += (size_t)N * sizeof(unsigned);
    float*    denom = (float*)ws;    ws += (size_t)N * sizeof(float);
    float*    s_src = (float*)ws;    ws += (size_t)N * sizeof(float);
    float*    s_tgt = (float*)ws;    ws += (size_t)N * sizeof(float);

    hipMemsetAsync(out,   0, (size_t)N * 64 * sizeof(float), stream);
    hipMemsetAsync(m_ord, 0, (size_t)N * sizeof(unsigned), stream);
    hipMemsetAsync(denom, 0, (size_t)N * sizeof(float), stream);

    k_h_scores<<<(N + 3) / 4, 256, 0, stream>>>(X, W, a, h, s_src, s_tgt, N);
    k_edge_max<<<(E + 255) / 256, 256, 0, stream>>>(src, tgt, s_src, s_tgt, e_buf, m_ord, E);
    k_edge_exp<<<(E + 255) / 256, 256, 0, stream>>>(tgt, m_ord, e_buf, denom, E);
    k_att    <<<(E + 255) / 256, 256, 0, stream>>>(tgt, denom, e_buf, E);

    long long total = (long long)E * 64;
    int blocks = (int)((total + 255) / 256);
    k_scatter<<<blocks, 256, 0, stream>>>(src, tgt, h, e_buf, out, E);

    int n_out = N * 64;
    k_elu<<<(n_out + 255) / 256, 256, 0, stream>>>(out, n_out);
}

// Round 2
// 305.223 us; speedup vs baseline: 1.9799x; 1.9799x over previous
//
#include <hip/hip_runtime.h>
#include <math.h>

#define ALPHA 0.2f

// ---------------- Kernel 1: h = X @ W, node scores s_src/s_tgt --------------
__global__ __launch_bounds__(256) void k_h_scores(
    const float* __restrict__ X, const float* __restrict__ W,
    const float* __restrict__ a, float* __restrict__ h,
    float* __restrict__ s_src, float* __restrict__ s_tgt, int N)
{
    __shared__ float Ws[64 * 64];
    __shared__ float xs[4][64];
    const int tid  = threadIdx.x;
    const int lane = tid & 63;
    const int wave = tid >> 6;
    const int row  = blockIdx.x * 4 + wave;

    for (int i = tid; i < 64 * 64; i += 256) Ws[i] = W[i];
    if (row < N) xs[wave][lane] = X[(size_t)row * 64 + lane];
    __syncthreads();

    if (row >= N) return;

    float acc = 0.f;
#pragma unroll
    for (int k = 0; k < 64; ++k) acc += xs[wave][k] * Ws[k * 64 + lane];

    h[(size_t)row * 64 + lane] = acc;

    float v1 = acc * a[lane];
    float v2 = acc * a[64 + lane];
#pragma unroll
    for (int off = 32; off > 0; off >>= 1) {
        v1 += __shfl_xor(v1, off);
        v2 += __shfl_xor(v2, off);
    }
    if (lane == 0) { s_src[row] = v1; s_tgt[row] = v2; }
}

// ---------------- CSR build: count / scan / fill ----------------------------
__global__ __launch_bounds__(256) void k_count(
    const int* __restrict__ tgt, int* __restrict__ deg, int E)
{
    int i = blockIdx.x * 256 + threadIdx.x;
    if (i >= E) return;
    atomicAdd(&deg[tgt[i]], 1);
}

// block-level inclusive scan; rowptr[i+1] = incl scan within block; bsum[b]=block total
__global__ __launch_bounds__(256) void k_scan1(
    const int* __restrict__ deg, int* __restrict__ rowptr,
    int* __restrict__ bsum, int N)
{
    __shared__ int tmp[256];
    int i = blockIdx.x * 256 + threadIdx.x;
    int v = (i < N) ? deg[i] : 0;
    tmp[threadIdx.x] = v;
    __syncthreads();
#pragma unroll
    for (int off = 1; off < 256; off <<= 1) {
        int t = (threadIdx.x >= off) ? tmp[threadIdx.x - off] : 0;
        __syncthreads();
        tmp[threadIdx.x] += t;
        __syncthreads();
    }
    if (i < N) rowptr[i + 1] = tmp[threadIdx.x];
    if (threadIdx.x == 255) bsum[blockIdx.x] = tmp[255];
    if (i == 0) rowptr[0] = 0;
}

// single-block exclusive scan of block sums (nb <= 1024)
__global__ __launch_bounds__(1024) void k_scan2(int* __restrict__ bsum, int nb)
{
    __shared__ int tmp[1024];
    int tid = threadIdx.x;
    int v = (tid < nb) ? bsum[tid] : 0;
    tmp[tid] = v;
    __syncthreads();
#pragma unroll
    for (int off = 1; off < 1024; off <<= 1) {
        int t = (tid >= off) ? tmp[tid - off] : 0;
        __syncthreads();
        tmp[tid] += t;
        __syncthreads();
    }
    if (tid < nb) bsum[tid] = (tid ? tmp[tid - 1] : 0);
}

__global__ __launch_bounds__(256) void k_scan3(
    int* __restrict__ rowptr, const int* __restrict__ bsum, int N)
{
    int i = blockIdx.x * 256 + threadIdx.x;
    if (i < N) rowptr[i + 1] += bsum[blockIdx.x];
}

// fill CSR edge list; consumes deg (decrements to 0)
__global__ __launch_bounds__(256) void k_fill(
    const int* __restrict__ src, const int* __restrict__ tgt,
    const int* __restrict__ rowptr, int* __restrict__ deg,
    int* __restrict__ elist, int E)
{
    int i = blockIdx.x * 256 + threadIdx.x;
    if (i >= E) return;
    int t = tgt[i];
    int old = atomicSub(&deg[t], 1);
    elist[rowptr[t] + old - 1] = src[i];
}

// ---------------- fused gather: softmax + weighted accumulation + ELU -------
// one wave per target node; no float atomics anywhere
__global__ __launch_bounds__(256) void k_gather(
    const int* __restrict__ rowptr, const int* __restrict__ elist,
    const float* __restrict__ s_src, const float* __restrict__ s_tgt,
    const float* __restrict__ h, float* __restrict__ out, int N)
{
    const int t    = blockIdx.x * 4 + (threadIdx.x >> 6);
    const int lane = threadIdx.x & 63;
    if (t >= N) return;

    const int beg = rowptr[t];
    const int end = rowptr[t + 1];
    const size_t orow = (size_t)t * 64 + lane;

    if (beg == end) { out[orow] = 0.f; return; }

    const float st = s_tgt[t];
    float acc = 0.f, den = 0.f;

    if (end - beg <= 64) {
        // common path (Poisson deg ~16): whole segment in one chunk, kept in regs
        const int idx = beg + lane;
        const int cnt = end - beg;
        int s = 0; float e = -INFINITY;
        if (idx < end) {
            s = elist[idx];
            float v = s_src[s] + st;
            e = (v >= 0.f) ? v : ALPHA * v;
        }
        float m = e;
#pragma unroll
        for (int off = 32; off > 0; off >>= 1) m = fmaxf(m, __shfl_xor(m, off));
        float p = (idx < end) ? __expf(e - m) : 0.f;
        den = p;
#pragma unroll
        for (int off = 32; off > 0; off >>= 1) den += __shfl_xor(den, off);

        int k = 0;
        for (; k + 4 <= cnt; k += 4) {
            int   s0 = __shfl(s, k+0), s1 = __shfl(s, k+1), s2 = __shfl(s, k+2), s3 = __shfl(s, k+3);
            float p0 = __shfl(p, k+0), p1 = __shfl(p, k+1), p2 = __shfl(p, k+2), p3 = __shfl(p, k+3);
            float h0 = h[(size_t)s0 * 64 + lane];
            float h1 = h[(size_t)s1 * 64 + lane];
            float h2 = h[(size_t)s2 * 64 + lane];
            float h3 = h[(size_t)s3 * 64 + lane];
            acc += p0 * h0; acc += p1 * h1; acc += p2 * h2; acc += p3 * h3;
        }
        for (; k < cnt; ++k)
            acc += __shfl(p, k) * h[(size_t)__shfl(s, k) * 64 + lane];
    } else {
        // rare path: degree > 64, two passes over chunks
        float m = -INFINITY;
        for (int base = beg; base < end; base += 64) {
            int idx = base + lane;
            float e = -INFINITY;
            if (idx < end) {
                int s = elist[idx];
                float v = s_src[s] + st;
                e = (v >= 0.f) ? v : ALPHA * v;
            }
            m = fmaxf(m, e);
        }
#pragma unroll
        for (int off = 32; off > 0; off >>= 1) m = fmaxf(m, __shfl_xor(m, off));

        for (int base = beg; base < end; base += 64) {
            int idx = base + lane;
            int cnt = min(64, end - base);
            int s = 0; float p = 0.f;
            if (idx < end) {
                int sv = elist[idx];
                s = sv;
                float v = s_src[sv] + st;
                v = (v >= 0.f) ? v : ALPHA * v;
                p = __expf(v - m);
            }
            den += p;
            int k = 0;
            for (; k + 4 <= cnt; k += 4) {
                int   s0 = __shfl(s, k+0), s1 = __shfl(s, k+1), s2 = __shfl(s, k+2), s3 = __shfl(s, k+3);
                float p0 = __shfl(p, k+0), p1 = __shfl(p, k+1), p2 = __shfl(p, k+2), p3 = __shfl(p, k+3);
                float h0 = h[(size_t)s0 * 64 + lane];
                float h1 = h[(size_t)s1 * 64 + lane];
                float h2 = h[(size_t)s2 * 64 + lane];
                float h3 = h[(size_t)s3 * 64 + lane];
                acc += p0 * h0; acc += p1 * h1; acc += p2 * h2; acc += p3 * h3;
            }
            for (; k < cnt; ++k)
                acc += __shfl(p, k) * h[(size_t)__shfl(s, k) * 64 + lane];
        }
#pragma unroll
        for (int off = 32; off > 0; off >>= 1) den += __shfl_xor(den, off);
    }

    float r = acc / den;
    out[orow] = (r > 0.f) ? r : expm1f(r);
}

extern "C" void kernel_launch(void* const* d_in, const int* in_sizes, int n_in,
                              void* d_out, int out_size, void* d_ws, size_t ws_size,
                              hipStream_t stream)
{
    const float* X  = (const float*)d_in[0];
    const int*   ei = (const int*)d_in[1];
    const float* W  = (const float*)d_in[2];
    const float* a  = (const float*)d_in[3];

    const int N = in_sizes[0] / 64;
    const int E = in_sizes[1] / 2;
    const int* src = ei;
    const int* tgt = ei + E;

    float* out = (float*)d_out;

    char* ws = (char*)d_ws;
    float* h      = (float*)ws; ws += (size_t)N * 64 * sizeof(float);
    float* s_src  = (float*)ws; ws += (size_t)N * sizeof(float);
    float* s_tgt  = (float*)ws; ws += (size_t)N * sizeof(float);
    int*   deg    = (int*)ws;   ws += (size_t)N * sizeof(int);
    int*   rowptr = (int*)ws;   ws += ((size_t)N + 1) * sizeof(int);
    int*   bsum   = (int*)ws;   ws += 1024 * sizeof(int);
    int*   elist  = (int*)ws;   ws += (size_t)E * sizeof(int);

    const int nb = (N + 255) / 256;  // scan blocks (must be <= 1024; 391 here)

    hipMemsetAsync(deg, 0, (size_t)N * sizeof(int), stream);

    k_h_scores<<<(N + 3) / 4, 256, 0, stream>>>(X, W, a, h, s_src, s_tgt, N);
    k_count   <<<(E + 255) / 256, 256, 0, stream>>>(tgt, deg, E);
    k_scan1   <<<nb, 256, 0, stream>>>(deg, rowptr, bsum, N);
    k_scan2   <<<1, 1024, 0, stream>>>(bsum, nb);
    k_scan3   <<<nb, 256, 0, stream>>>(rowptr, bsum, N);
    k_fill    <<<(E + 255) / 256, 256, 0, stream>>>(src, tgt, rowptr, deg, elist, E);
    k_gather  <<<(N + 3) / 4, 256, 0, stream>>>(rowptr, elist, s_src, s_tgt, h, out, N);
}